// Round 8
// baseline (37.604 us; speedup 1.0000x reference)
//
#include <hip/hip_runtime.h>
#include <math.h>

#define D 20
#define NROWS 1000000
#define NTILES (NROWS / 16)            // 62500 16-row tiles
#define TPB 256
#define TILES_PER_BLK 16               // 16 tiles * 1280 B = 20 KB staged/block
#define NSB ((NTILES + TILES_PER_BLK - 1) / TILES_PER_BLK)   // 3907 blocks
#define NF4 (NROWS * D / 4)            // 5,000,000 float4s in X
#define F4_PER_SB (TILES_PER_BLK * 16 * D / 4)               // 1280 float4/superblock

typedef float  f32x4  __attribute__((ext_vector_type(4)));
typedef __bf16 bf16x8 __attribute__((ext_vector_type(8)));

// ws layout: [0, NSB*16) per-block partials (S, Sabs) doubles = 62512 B.
// Every slot is written before final_kernel reads it -> poison/replay safe.

// ---------------------------------------------------------------------------
// MAIN (setup folded in). Per block:
//  1) stage X superblock (5 coalesced float4/thread) + W/R/b (coalesced) -> LDS
//  2) fold A = W^T R, c = bR + 1 in LDS (420 dots of 20 FMA, 2 passes)
//  3) each thread builds its lane's 4 MFMA const fragments from LDS
//     (B1: A^T rows, k==20 slot = c ; B2: W cols, SIGMA-permuted k-rows
//      sigma(G,e)= e<4 ? 4G+e : 16+4G+(e-4), slot sigma==20 = b[n] -- permutation
//      makes GEMM1 acc regs feed GEMM2's A-frag with no cross-lane ops)
//  4) compute 4 tiles/wave; fragment loads use per-lane base+stride pointing
//     either at real rows or at a tiny LDS zero/one zone (stride 0) -> the
//     fragment build is 8 straight f32->bf16 converts, zero selects.
// ---------------------------------------------------------------------------
__global__ __launch_bounds__(TPB) void main_kernel(
    const float* __restrict__ X, const float* __restrict__ W,
    const float* __restrict__ b, const float* __restrict__ R,
    double* __restrict__ partial) {
  __shared__ float4 xs4[F4_PER_SB + 2];   // 20 KB + 32 B const zones
  __shared__ float4 Wv[D * D / 4];        // staged W (400 f)
  __shared__ float4 Rv[D * D / 4];        // staged R (400 f)
  __shared__ float  b_s[D];
  __shared__ float  A_s[D * D];
  __shared__ float  c_s[D];
  __shared__ double red[8];
  float* xs  = (float*)xs4;
  float* W_s = (float*)Wv;
  float* R_s = (float*)Rv;
  const int t = threadIdx.x;
  const int s = blockIdx.x;

  // ---- 1) stage: X fully coalesced; W/R/b coalesced; const zones ----
  const float4* X4 = (const float4*)X;
#pragma unroll
  for (int j = 0; j < 5; ++j) {
    int gi = s * F4_PER_SB + j * TPB + t;
    gi = (gi < NF4) ? gi : (NF4 - 1);            // tail: garbage, guarded below
    xs4[j * TPB + t] = X4[gi];
  }
  if (t < 100) Wv[t] = ((const float4*)W)[t];
  else if (t < 200) Rv[t - 100] = ((const float4*)R)[t - 100];
  else if (t < 220) b_s[t - 200] = b[t - 200];
  else if (t < 228) xs[4 * F4_PER_SB + (t - 220)] = (t == 220) ? 1.0f : 0.0f;
  __syncthreads();

  // ---- 2) fold A = W^T R (A[j][m] = sum_i W[i][j]R[i][m]), c = bR + 1 ----
  for (int q = t; q < D * D + D; q += TPB) {
    if (q < D * D) {
      int j = q / D, m = q % D;
      float acc = 0.f;
#pragma unroll
      for (int i = 0; i < D; ++i) acc = fmaf(W_s[i * D + j], R_s[i * D + m], acc);
      A_s[q] = acc;
    } else {
      int m = q - D * D;
      float acc = 1.0f;
#pragma unroll
      for (int i = 0; i < D; ++i) acc = fmaf(b_s[i], R_s[i * D + m], acc);
      c_s[m] = acc;
    }
  }
  __syncthreads();

  // ---- 3) per-lane constant fragments from LDS ----
  const int lane = t & 63;
  const int G = lane >> 4, ii = lane & 15;
  const int wid = t >> 6;
  bf16x8 B1t1, B1t2, B2t1, B2t2;
#pragma unroll
  for (int e = 0; e < 8; ++e) {
    int k = G * 8 + e;
    int kc = (k < D) ? k : (D - 1);
    float v1 = A_s[kc * D + ii];
    B1t1[e] = (__bf16)((k < D) ? v1 : (k == D ? c_s[ii] : 0.f));
    int m2 = 16 + ii;                            // only ii<4 valid
    float v2 = (m2 < D) ? A_s[kc * D + m2] : 0.f;
    B1t2[e] = (__bf16)((m2 < D) ? ((k < D) ? v2 : (k == D ? c_s[m2] : 0.f)) : 0.f);
    int sg = (e < 4) ? (4 * G + e) : (16 + 4 * G + (e - 4));
    int sgc = (sg < D) ? sg : (D - 1);
    float v3 = W_s[ii * D + sgc];
    B2t1[e] = (__bf16)((sg < D) ? v3 : (sg == D ? b_s[ii] : 0.f));
    float v4 = (m2 < D) ? W_s[m2 * D + sgc] : 0.f;
    B2t2[e] = (__bf16)((m2 < D) ? ((sg < D) ? v4 : (sg == D ? b_s[m2] : 0.f)) : 0.f);
  }

  // ---- 4) compute: 4 tiles/wave; zero-region bases, no per-tile selects ----
  // lane's X-frag k-slots: G*8+e. G<2: all real; G==2: k=16..19 real then
  // {1,0,0,0} (k==20 -> 1.0 feeds the c-slot); G==3: all zero.
  float* zC = xs + 4 * F4_PER_SB;                // {1,0,0,0}
  float* zZ = zC + 4;                            // {0,0,0,0}
  const float* caBase; int caStr;
  const float* cbBase; int cbStr;
  if (G < 2)       { caBase = xs + ii * D + G * 8; caStr = 16 * D;
                     cbBase = caBase + 4;          cbStr = 16 * D; }
  else if (G == 2) { caBase = xs + ii * D + 16;    caStr = 16 * D;
                     cbBase = zC;                  cbStr = 0; }
  else             { caBase = zZ;                  caStr = 0;
                     cbBase = zZ;                  cbStr = 0; }

  double s64 = 0.0, sa64 = 0.0;
#pragma unroll
  for (int k = 0; k < 4; ++k) {
    const int wt = wid * 4 + k;
    if (s * TILES_PER_BLK + wt < NTILES) {       // wave-uniform guard (tail)
      const float4 ca = *(const float4*)(caBase + wt * caStr);
      const float4 cb = *(const float4*)(cbBase + wt * cbStr);
      bf16x8 xf;
      xf[0] = (__bf16)ca.x; xf[1] = (__bf16)ca.y;
      xf[2] = (__bf16)ca.z; xf[3] = (__bf16)ca.w;
      xf[4] = (__bf16)cb.x; xf[5] = (__bf16)cb.y;
      xf[6] = (__bf16)cb.z; xf[7] = (__bf16)cb.w;

      const f32x4 zz = {0.f, 0.f, 0.f, 0.f};
      f32x4 a1 = __builtin_amdgcn_mfma_f32_16x16x32_bf16(B1t1, xf, zz, 0, 0, 0);
      f32x4 a2 = __builtin_amdgcn_mfma_f32_16x16x32_bf16(B1t2, xf, zz, 0, 0, 0);
#pragma unroll
      for (int q = 0; q < 4; ++q) {
        a1[q] = fmaxf(a1[q], 0.f);
        a2[q] = fmaxf(a2[q], 0.f);
      }
      const float hj = (G == 1) ? 1.0f : a2[0];  // m=20 slot carries 1.0 (b-row)
      bf16x8 x2f;
      x2f[0] = (__bf16)a1[0]; x2f[1] = (__bf16)a1[1];
      x2f[2] = (__bf16)a1[2]; x2f[3] = (__bf16)a1[3];
      x2f[4] = (__bf16)hj;    x2f[5] = (__bf16)a2[1];
      x2f[6] = (__bf16)a2[2]; x2f[7] = (__bf16)a2[3];

      f32x4 z1 = __builtin_amdgcn_mfma_f32_16x16x32_bf16(x2f, B2t1, zz, 0, 0, 0);
      f32x4 z2 = __builtin_amdgcn_mfma_f32_16x16x32_bf16(x2f, B2t2, zz, 0, 0, 0);

      const float s8 = ((z1[0] + z1[1]) + (z1[2] + z1[3])) +
                       ((z2[0] + z2[1]) + (z2[2] + z2[3]));
      const float sa8 =
          ((fabsf(z1[0]) + fabsf(z1[1])) + (fabsf(z1[2]) + fabsf(z1[3]))) +
          ((fabsf(z2[0]) + fabsf(z2[1])) + (fabsf(z2[2]) + fabsf(z2[3])));
      s64 += (double)s8;
      sa64 += (double)sa8;
    }
  }

  // ---- block reduce: wave64 shfl (f64) -> 4-wave LDS -> one pair/block ----
#pragma unroll
  for (int off = 32; off > 0; off >>= 1) {
    s64 += __shfl_down(s64, off, 64);
    sa64 += __shfl_down(sa64, off, 64);
  }
  if ((t & 63) == 0) { red[wid * 2] = s64; red[wid * 2 + 1] = sa64; }
  __syncthreads();
  if (t == 0) {
    partial[2 * s]     = red[0] + red[2] + red[4] + red[6];
    partial[2 * s + 1] = red[1] + red[3] + red[5] + red[7];
  }
}

// ---------------------------------------------------------------------------
// Finalize: reduce NSB partial pairs in fixed order; halving loop is exact
// scalar math: k = #halvings until abs-sum <= 1; out = ldexp(S, -k).
// ---------------------------------------------------------------------------
__global__ __launch_bounds__(256) void final_kernel(
    const double* __restrict__ partial, float* __restrict__ out) {
  double s = 0.0, sa = 0.0;
  for (int i = threadIdx.x; i < NSB; i += 256) {
    s += partial[2 * i];
    sa += partial[2 * i + 1];
  }
#pragma unroll
  for (int off = 32; off > 0; off >>= 1) {
    s += __shfl_down(s, off, 64);
    sa += __shfl_down(sa, off, 64);
  }
  __shared__ double red[8];
  int wid = threadIdx.x >> 6;
  if ((threadIdx.x & 63) == 0) { red[wid * 2] = s; red[wid * 2 + 1] = sa; }
  __syncthreads();
  if (threadIdx.x == 0) {
    double S  = red[0] + red[2] + red[4] + red[6];
    double SA = red[1] + red[3] + red[5] + red[7];
    int k = 0;
    double t = SA;
    while (t > 1.0 && k < 4096) { t *= 0.5; ++k; }  // exact: /2 per ref iter
    out[0] = (float)ldexp(S, -k);
  }
}

extern "C" void kernel_launch(void* const* d_in, const int* in_sizes, int n_in,
                              void* d_out, int out_size, void* d_ws, size_t ws_size,
                              hipStream_t stream) {
  const float* X = (const float*)d_in[0];
  const float* W = (const float*)d_in[1];
  const float* b = (const float*)d_in[2];
  const float* R = (const float*)d_in[3];
  double* partial = (double*)d_ws;

  main_kernel<<<NSB, TPB, 0, stream>>>(X, W, b, R, partial);
  final_kernel<<<1, 256, 0, stream>>>(partial, (float*)d_out);
}